// Round 15
// baseline (64.926 us; speedup 1.0000x reference)
//
#include <hip/hip_runtime.h>
#include <hip/hip_bf16.h>
#include <cstdint>
#include <cstddef>

#define B_ROWS 8192
#define KDIM   4096
#define IN_DIM 2048
#define HIDDEN 2048
#define NJ     32           // 4 gates x 8 wires
#define BK     64           // k-subtile per pipeline stage
#define SUBT   (KDIM / BK)  // 64 subtiles: FULL K per block
#define MROWS  16           // rows per block (ONE wave)
#define TPB1   64           // 1 wave -> no s_barrier anywhere
#define NBUF   4            // depth-3 prefetch (single-wave sequential: safe)
#define GRID1  (B_ROWS / MROWS) // 512 blocks -> 2 independent pipelines/CU

typedef __bf16 bf16x8 __attribute__((ext_vector_type(8)));
typedef float  f32x4  __attribute__((ext_vector_type(4)));

__device__ __forceinline__ bf16x8 cvt8(f32x4 a, f32x4 b) {
    bf16x8 r;
    r[0] = (__bf16)a.x; r[1] = (__bf16)a.y; r[2] = (__bf16)a.z; r[3] = (__bf16)a.w;
    r[4] = (__bf16)b.x; r[5] = (__bf16)b.y; r[6] = (__bf16)b.z; r[7] = (__bf16)b.w;
    return r;
}

// async global->LDS, 16 B per lane; LDS dest = wave-uniform base + lane*16
__device__ __forceinline__ void gload_lds16(const void* g, void* lds) {
    __builtin_amdgcn_global_load_lds(
        (const __attribute__((address_space(1))) void*)g,
        (__attribute__((address_space(3))) void*)lds, 16, 0, 0);
}

// ==== Pass 1: full-K MFMA GEMM + bias + cos + wave reduce -> qpart[512][4] ==
// grid = 512 blocks of 64 thr (1 wave); block = 16 rows x K=4096.
// LDS/buf: A fp32 [16][64] (4 KB) + W fp32 [32][64] (8 KB) = 12 KB; NBUF=4
// -> 48 KB/block; 512 blocks = 2 blocks/CU, independent depth-3 pipelines.
// XOR swizzle both sides (rule #21): 16B-unit u ^= (row & 7).
// NO Spart, NO p2, NO atomics: complete dots in-register -> cos -> 4 floats.
extern "C" __global__ __launch_bounds__(TPB1)
void p1_full(const float* __restrict__ x,  const float* __restrict__ hx,
             const float* __restrict__ Wf, const float* __restrict__ Wi,
             const float* __restrict__ Wg, const float* __restrict__ Wo,
             const float* __restrict__ bfp, const float* __restrict__ bip,
             const float* __restrict__ bgp, const float* __restrict__ bop,
             float* __restrict__ qpart)
{
    __shared__ float Abuf[NBUF][MROWS * BK];   // 4 x 4 KB
    __shared__ float Bbuf[NBUF][NJ * BK];      // 4 x 8 KB

    const int lane = threadIdx.x & 63;
    const int lrow = lane & 15;
    const int rowblk = blockIdx.x * MROWS;

    // A: k<2048 from x, k>=2048 from hx (both row-stride 2048)
    const float* Ax = x  + (size_t)rowblk * IN_DIM;
    const float* Ah = hx + (size_t)rowblk * HIDDEN;

    // ---- A staging (pre-swizzled source; r13/r14-verified) ----
    // instr p: row r = p*4 + (l>>4), dest unit l&15, src unit = (l&15)^(r&7)
    int aOff[4];
#pragma unroll
    for (int p = 0; p < 4; ++p) {
        const int r  = p * 4 + (lane >> 4);
        const int cs = (lane & 15) ^ (r & 7);
        aOff[p] = r * 2048 + cs * 4;            // float offset
    }
    // ---- W staging (r11/r14-verified slab addressing) ----
    // slab sl: rows j = sl*4 + (l>>4); gate = j>>3; src off within gate:
    // (j&7)*KDIM + ((l&15)^(j&7))*4 floats
    const float* Wsrc[8] = {Wf, Wf, Wi, Wi, Wg, Wg, Wo, Wo};
    int bOffp[8];
#pragma unroll
    for (int sl = 0; sl < 8; ++sl) {
        const int j  = sl * 4 + (lane >> 4);
        const int j7 = j & 7;
        bOffp[sl] = j7 * KDIM + (((lane & 15) ^ j7) * 4);   // float offset
    }

    // ---- swizzled ds_read_b128 byte offsets (256 B row pitch, fp32) ----
    int offA0[2], offA1[2], offB00[2], offB01[2], offB10[2], offB11[2];
#pragma unroll
    for (int st = 0; st < 2; ++st) {
        const int cu = st * 8 + (lane >> 4) * 2;
        offA0[st]  = lrow * 256 + (((cu + 0) ^ (lane & 7)) * 16);
        offA1[st]  = lrow * 256 + (((cu + 1) ^ (lane & 7)) * 16);
        offB00[st] = lrow * 256        + (((cu + 0) ^ (lane & 7)) * 16);
        offB01[st] = lrow * 256        + (((cu + 1) ^ (lane & 7)) * 16);
        offB10[st] = (lrow + 16) * 256 + (((cu + 0) ^ (lane & 7)) * 16);
        offB11[st] = (lrow + 16) * 256 + (((cu + 1) ^ (lane & 7)) * 16);
    }

    f32x4 acc0 = {0.f, 0.f, 0.f, 0.f};   // j = lrow      (gates f,i)
    f32x4 acc1 = {0.f, 0.f, 0.f, 0.f};   // j = 16 + lrow (gates g,o)

    auto issue = [&](int s) {
        const int b = s & (NBUF - 1);
        const float* As = (s < SUBT / 2) ? (Ax + s * BK)
                                         : (Ah + (s - SUBT / 2) * BK);
#pragma unroll
        for (int p = 0; p < 4; ++p)
            gload_lds16(As + aOff[p], (char*)&Abuf[b][0] + p * 1024);
#pragma unroll
        for (int sl = 0; sl < 8; ++sl)
            gload_lds16(Wsrc[sl] + bOffp[sl] + s * BK,
                        (char*)&Bbuf[b][0] + sl * 1024);
    };
    auto compute = [&](int s) {
        const int b = s & (NBUF - 1);
        const char* Ab = (const char*)&Abuf[b][0];
        const char* Bb = (const char*)&Bbuf[b][0];
#pragma unroll
        for (int st = 0; st < 2; ++st) {
            f32x4 a0  = *reinterpret_cast<const f32x4*>(Ab + offA0[st]);
            f32x4 a1  = *reinterpret_cast<const f32x4*>(Ab + offA1[st]);
            f32x4 w00 = *reinterpret_cast<const f32x4*>(Bb + offB00[st]);
            f32x4 w01 = *reinterpret_cast<const f32x4*>(Bb + offB01[st]);
            f32x4 w10 = *reinterpret_cast<const f32x4*>(Bb + offB10[st]);
            f32x4 w11 = *reinterpret_cast<const f32x4*>(Bb + offB11[st]);
            bf16x8 af  = cvt8(a0, a1);
            bf16x8 bf0 = cvt8(w00, w01);
            bf16x8 bf1 = cvt8(w10, w11);
            acc0 = __builtin_amdgcn_mfma_f32_16x16x32_bf16(af, bf0, acc0, 0, 0, 0);
            acc1 = __builtin_amdgcn_mfma_f32_16x16x32_bf16(af, bf1, acc1, 0, 0, 0);
        }
    };

    // ---- BARRIER-FREE pipeline: depth-3 prefetch, counted per-wave vmcnt.
    // 12 loads/batch; outstanding after issue(s+3) = {s+1,s+2,s+3} = 36
    // -> vmcnt(36) implies batch s landed. Tail: 24, 12, 0.
    // Buffer safety (single wave, sequential): writer at iter s targets buf
    // (s+3)%4; the only concurrent reader is compute(s) on buf s%4 --
    // distance 3 mod 4 != 0; prior contents of (s+3)%4 were consumed at
    // compute(s-1), which precedes issue(s+3) in program order.
    issue(0);
    issue(1);
    issue(2);
#pragma unroll 4
    for (int s = 0; s < SUBT; ++s) {
        if (s + 3 < SUBT) issue(s + 3);
        if (s < SUBT - 3)
            asm volatile("s_waitcnt vmcnt(36)" ::: "memory");
        else if (s == SUBT - 3)
            asm volatile("s_waitcnt vmcnt(24)" ::: "memory");
        else if (s == SUBT - 2)
            asm volatile("s_waitcnt vmcnt(12)" ::: "memory");
        else
            asm volatile("s_waitcnt vmcnt(0)" ::: "memory");
        __builtin_amdgcn_sched_barrier(0);      // no ds_read hoist (rule #18)
        compute(s);
    }

    // ---- epilogue (r11-verified): bias + cos + wave reduce, 4 stores ----
    // acc0[r] = full dot(row m0+r, j=lrow); acc1[r] = dot(row m0+r, 16+lrow)
    const float b0v = ((lrow & 8) ? bip : bfp)[lrow & 7];   // gate f / i
    const float b1v = ((lrow & 8) ? bop : bgp)[lrow & 7];   // gate g / o
    float v0 = 0.f, v1 = 0.f;
#pragma unroll
    for (int r = 0; r < 4; ++r) {
        v0 += cosf(acc0[r] + b0v);
        v1 += cosf(acc1[r] + b1v);
    }
    // reduce over the 32 lanes sharing lane-bit3 (gate class): XOR bits
    // {0,1,2,4,5}; afterwards lanes 0 and 8 hold the two gate totals each.
    v0 += __shfl_xor(v0, 1, 64);  v1 += __shfl_xor(v1, 1, 64);
    v0 += __shfl_xor(v0, 2, 64);  v1 += __shfl_xor(v1, 2, 64);
    v0 += __shfl_xor(v0, 4, 64);  v1 += __shfl_xor(v1, 4, 64);
    v0 += __shfl_xor(v0, 16, 64); v1 += __shfl_xor(v1, 16, 64);
    v0 += __shfl_xor(v0, 32, 64); v1 += __shfl_xor(v1, 32, 64);
    if ((lane & 55) == 0) {                     // lanes 0 and 8
        const int gg = (lane >> 3) & 1;
        qpart[blockIdx.x * 4 + gg]     = v0;    // gates f(0)/i(1)
        qpart[blockIdx.x * 4 + gg + 2] = v1;    // gates g(2)/o(3)
    }
}

// ======= Pass 2: reduce qpart[512][4] + elementwise LSTM update ===========
// cx: NORMAL load (re-read every replay -> keep L3-resident).
// out: NON-TEMPORAL store (write-once stream -> don't evict inputs from L3).
extern "C" __global__ __launch_bounds__(256)
void p3_elementwise(const float* __restrict__ cx, const float* __restrict__ qpart,
                    float* __restrict__ out)
{
    __shared__ float qs[4][4];                  // [wave][gate]
    const int tid  = threadIdx.x;
    const int wave = tid >> 6;
    const int lane = tid & 63;

    // block-local reduce of qpart[512][4]: two f32x4 per thread
    const f32x4* qp4 = (const f32x4*)qpart;
    f32x4 qa = qp4[tid];
    f32x4 qb = qp4[tid + 256];
    f32x4 qp = {qa.x + qb.x, qa.y + qb.y, qa.z + qb.z, qa.w + qb.w};
#pragma unroll
    for (int m = 1; m <= 32; m <<= 1) {
        qp.x += __shfl_xor(qp.x, m, 64);
        qp.y += __shfl_xor(qp.y, m, 64);
        qp.z += __shfl_xor(qp.z, m, 64);
        qp.w += __shfl_xor(qp.w, m, 64);
    }
    if (lane == 0) {
        qs[wave][0] = qp.x; qs[wave][1] = qp.y;
        qs[wave][2] = qp.z; qs[wave][3] = qp.w;
    }
    __syncthreads();
    const float qf = qs[0][0] + qs[1][0] + qs[2][0] + qs[3][0];
    const float qi = qs[0][1] + qs[1][1] + qs[2][1] + qs[3][1];
    const float qg = qs[0][2] + qs[1][2] + qs[2][2] + qs[3][2];
    const float qo = qs[0][3] + qs[1][3] + qs[2][3] + qs[3][3];

    const float f  = 1.f / (1.f + expf(-qf));
    const float ii = 1.f / (1.f + expf(-qi));
    const float g  = tanhf(qg);
    const float o  = 1.f / (1.f + expf(-qo));
    const float ig = ii * g;

    const size_t N  = (size_t)B_ROWS * HIDDEN;
    const size_t N4 = N >> 2;
    const f32x4* cx4 = (const f32x4*)cx;
    f32x4* outh = (f32x4*)out;
    f32x4* outc = (f32x4*)(out + N);

    for (size_t idx = (size_t)blockIdx.x * blockDim.x + tid; idx < N4;
         idx += (size_t)gridDim.x * blockDim.x) {
        f32x4 c = cx4[idx];                       // L3-resident across replays
        f32x4 cn, hn;
        cn.x = fmaf(f, c.x, ig);
        cn.y = fmaf(f, c.y, ig);
        cn.z = fmaf(f, c.z, ig);
        cn.w = fmaf(f, c.w, ig);
        hn.x = o * tanhf(cn.x);
        hn.y = o * tanhf(cn.y);
        hn.z = o * tanhf(cn.z);
        hn.w = o * tanhf(cn.w);
        __builtin_nontemporal_store(cn, outc + idx);
        __builtin_nontemporal_store(hn, outh + idx);
    }
}

// ---------------- launcher: TWO dispatches, no atomics, no memset ---------
extern "C" void kernel_launch(void* const* d_in, const int* in_sizes, int n_in,
                              void* d_out, int out_size, void* d_ws, size_t ws_size,
                              hipStream_t stream)
{
    const float* x  = (const float*)d_in[0];
    const float* hx = (const float*)d_in[1];
    const float* cx = (const float*)d_in[2];
    const float* Wf = (const float*)d_in[3];
    const float* bf = (const float*)d_in[4];
    const float* Wi = (const float*)d_in[5];
    const float* bi = (const float*)d_in[6];
    const float* Wg = (const float*)d_in[7];
    const float* bg = (const float*)d_in[8];
    const float* Wo = (const float*)d_in[9];
    const float* bo = (const float*)d_in[10];
    float* out = (float*)d_out;

    float* qpart = (float*)d_ws;   // [512][4] f32, fully overwritten each call

    p1_full<<<dim3(GRID1), dim3(TPB1), 0, stream>>>(
        x, hx, Wf, Wi, Wg, Wo, bf, bi, bg, bo, qpart);
    p3_elementwise<<<dim3(2048), dim3(256), 0, stream>>>(cx, qpart, out);
}

// Round 16
// 64.733 us; speedup vs baseline: 1.0030x; 1.0030x over previous
//
#include <hip/hip_runtime.h>
#include <hip/hip_bf16.h>
#include <cstdint>
#include <cstddef>

#define B_ROWS 8192
#define KDIM   4096
#define IN_DIM 2048
#define HIDDEN 2048
#define NJ     32            // 4 gates x 8 wires
#define BK     64            // k-subtile per pipeline stage
#define KHALF  2048          // per-wave K range (wave0: x, wave1: hx)
#define SUBT   (KHALF / BK)  // 32 subtiles per wave
#define MROWS  16            // rows per block
#define TPB1   128           // 2 waves, each an independent DMA pipeline
#define NBUF   3             // depth-2 prefetch (per-wave sequential: safe)
#define GRID1  (B_ROWS / MROWS) // 512 blocks -> 2 blocks/CU -> 4 pipelines/CU

typedef __bf16 bf16x8 __attribute__((ext_vector_type(8)));
typedef float  f32x4  __attribute__((ext_vector_type(4)));

__device__ __forceinline__ bf16x8 cvt8(f32x4 a, f32x4 b) {
    bf16x8 r;
    r[0] = (__bf16)a.x; r[1] = (__bf16)a.y; r[2] = (__bf16)a.z; r[3] = (__bf16)a.w;
    r[4] = (__bf16)b.x; r[5] = (__bf16)b.y; r[6] = (__bf16)b.z; r[7] = (__bf16)b.w;
    return r;
}

// async global->LDS, 16 B per lane; LDS dest = wave-uniform base + lane*16
__device__ __forceinline__ void gload_lds16(const void* g, void* lds) {
    __builtin_amdgcn_global_load_lds(
        (const __attribute__((address_space(1))) void*)g,
        (__attribute__((address_space(3))) void*)lds, 16, 0, 0);
}

// == Pass 1: full-K GEMM (K split across 2 waves) + cos + reduce -> qpart ==
// Block = 128 thr = 2 waves x 16 rows. Wave w owns k in [w*2048, w*2048+2048):
// wave 0 streams x, wave 1 streams hx -- each a BARRIER-FREE depth-2
// global_load_lds pipeline on private LDS buffers (vmcnt is per-wave).
// LDS: per wave A fp32 [16][64] (4 KB) + W fp32 [32][64] (8 KB), NBUF=3
// -> 72 KB/block -> 2 blocks/CU -> 4 independent pipelines/CU (r14 parity).
// Epilogue: one 2 KB LDS hand-off + 2 syncs, bias+cos+XOR-reduce (r15-
// verified), 4 floats to qpart[512][4]. No Spart, no p2, no atomics.
extern "C" __global__ __launch_bounds__(TPB1)
void p1_full(const float* __restrict__ x,  const float* __restrict__ hx,
             const float* __restrict__ Wf, const float* __restrict__ Wi,
             const float* __restrict__ Wg, const float* __restrict__ Wo,
             const float* __restrict__ bfp, const float* __restrict__ bip,
             const float* __restrict__ bgp, const float* __restrict__ bop,
             float* __restrict__ qpart)
{
    __shared__ float Abuf[2][NBUF][MROWS * BK];   // 2 x 3 x 4 KB
    __shared__ float Bbuf[2][NBUF][NJ * BK];      // 2 x 3 x 8 KB

    const int tid  = threadIdx.x;
    const int wave = tid >> 6;                    // 0..1
    const int lane = tid & 63;
    const int lrow = lane & 15;
    const int rowblk = blockIdx.x * MROWS;

    // wave 0: x rows (k base 0); wave 1: hx rows (k base 2048)
    const float* Aglob = (wave == 0)
        ? (x  + (size_t)rowblk * IN_DIM)
        : (hx + (size_t)rowblk * HIDDEN);
    const int kw = wave * KHALF;                  // W k-offset for this wave

    // ---- A staging (pre-swizzled source; r13/r14-verified) ----
    // instr p: row r = p*4 + (l>>4), dest unit l&15, src unit = (l&15)^(r&7)
    int aOff[4];
#pragma unroll
    for (int p = 0; p < 4; ++p) {
        const int r  = p * 4 + (lane >> 4);
        const int cs = (lane & 15) ^ (r & 7);
        aOff[p] = r * 2048 + cs * 4;              // float offset
    }
    // ---- W staging (r11/r14-verified slab addressing) ----
    // slab sl: rows j = sl*4 + (l>>4); gate = j>>3; src off within gate:
    // (j&7)*KDIM + ((l&15)^(j&7))*4 floats
    const float* Wsrc[8] = {Wf, Wf, Wi, Wi, Wg, Wg, Wo, Wo};
    int bOffp[8];
#pragma unroll
    for (int sl = 0; sl < 8; ++sl) {
        const int j  = sl * 4 + (lane >> 4);
        const int j7 = j & 7;
        bOffp[sl] = j7 * KDIM + (((lane & 15) ^ j7) * 4);   // float offset
    }

    // ---- swizzled ds_read_b128 byte offsets (256 B row pitch, fp32) ----
    int offA0[2], offA1[2], offB00[2], offB01[2], offB10[2], offB11[2];
#pragma unroll
    for (int st = 0; st < 2; ++st) {
        const int cu = st * 8 + (lane >> 4) * 2;
        offA0[st]  = lrow * 256 + (((cu + 0) ^ (lane & 7)) * 16);
        offA1[st]  = lrow * 256 + (((cu + 1) ^ (lane & 7)) * 16);
        offB00[st] = lrow * 256        + (((cu + 0) ^ (lane & 7)) * 16);
        offB01[st] = lrow * 256        + (((cu + 1) ^ (lane & 7)) * 16);
        offB10[st] = (lrow + 16) * 256 + (((cu + 0) ^ (lane & 7)) * 16);
        offB11[st] = (lrow + 16) * 256 + (((cu + 1) ^ (lane & 7)) * 16);
    }

    f32x4 acc0 = {0.f, 0.f, 0.f, 0.f};   // j = lrow      (gates f,i)
    f32x4 acc1 = {0.f, 0.f, 0.f, 0.f};   // j = 16 + lrow (gates g,o)

    auto issue = [&](int s) {
        const int b = s % NBUF;
#pragma unroll
        for (int p = 0; p < 4; ++p)
            gload_lds16(Aglob + aOff[p] + s * BK,
                        (char*)&Abuf[wave][b][0] + p * 1024);
#pragma unroll
        for (int sl = 0; sl < 8; ++sl)
            gload_lds16(Wsrc[sl] + bOffp[sl] + kw + s * BK,
                        (char*)&Bbuf[wave][b][0] + sl * 1024);
    };
    auto compute = [&](int s) {
        const int b = s % NBUF;
        const char* Ab = (const char*)&Abuf[wave][b][0];
        const char* Bb = (const char*)&Bbuf[wave][b][0];
#pragma unroll
        for (int st = 0; st < 2; ++st) {
            f32x4 a0  = *reinterpret_cast<const f32x4*>(Ab + offA0[st]);
            f32x4 a1  = *reinterpret_cast<const f32x4*>(Ab + offA1[st]);
            f32x4 w00 = *reinterpret_cast<const f32x4*>(Bb + offB00[st]);
            f32x4 w01 = *reinterpret_cast<const f32x4*>(Bb + offB01[st]);
            f32x4 w10 = *reinterpret_cast<const f32x4*>(Bb + offB10[st]);
            f32x4 w11 = *reinterpret_cast<const f32x4*>(Bb + offB11[st]);
            bf16x8 af  = cvt8(a0, a1);
            bf16x8 bf0 = cvt8(w00, w01);
            bf16x8 bf1 = cvt8(w10, w11);
            acc0 = __builtin_amdgcn_mfma_f32_16x16x32_bf16(af, bf0, acc0, 0, 0, 0);
            acc1 = __builtin_amdgcn_mfma_f32_16x16x32_bf16(af, bf1, acc1, 0, 0, 0);
        }
    };

    // ---- BARRIER-FREE per-wave pipeline (r14 geometry): depth-2 prefetch.
    // 12 loads/wave/batch; outstanding after issue(s+2) = {s+1,s+2} = 24
    // -> vmcnt(24) implies batch s landed. Tail: 12, then 0.
    // Buffer safety (per-wave sequential): writer at iter s targets buf
    // (s+2)%3; the only reader is compute(s) on buf s%3 -- distance 2 mod 3.
    issue(0);
    issue(1);
    for (int s = 0; s < SUBT - 2; ++s) {
        issue(s + 2);
        asm volatile("s_waitcnt vmcnt(24)" ::: "memory");
        __builtin_amdgcn_sched_barrier(0);        // no ds_read hoist (rule #18)
        compute(s);
    }
    asm volatile("s_waitcnt vmcnt(12)" ::: "memory");
    __builtin_amdgcn_sched_barrier(0);
    compute(SUBT - 2);
    asm volatile("s_waitcnt vmcnt(0)" ::: "memory");
    __builtin_amdgcn_sched_barrier(0);
    compute(SUBT - 1);

    // ---- merge wave 1's partial accs into wave 0 (one 2 KB LDS hand-off) --
    float* scratch = &Abuf[0][0][0];              // reuse; both pipelines done
    __syncthreads();                              // all K-loop LDS reads done
    if (wave == 1) {
        f32x4* sp = reinterpret_cast<f32x4*>(scratch);
        sp[lane * 2]     = acc0;
        sp[lane * 2 + 1] = acc1;
    }
    __syncthreads();
    if (wave == 0) {
        const f32x4* sp = reinterpret_cast<const f32x4*>(scratch);
        acc0 += sp[lane * 2];
        acc1 += sp[lane * 2 + 1];

        // ---- epilogue (r11/r15-verified): bias + cos + XOR reduce ----
        const float b0v = ((lrow & 8) ? bip : bfp)[lrow & 7];   // gate f / i
        const float b1v = ((lrow & 8) ? bop : bgp)[lrow & 7];   // gate g / o
        float v0 = 0.f, v1 = 0.f;
#pragma unroll
        for (int r = 0; r < 4; ++r) {
            v0 += cosf(acc0[r] + b0v);
            v1 += cosf(acc1[r] + b1v);
        }
        // reduce over the 32 lanes sharing lane-bit3 (gate class): XOR bits
        // {0,1,2,4,5}; afterwards lanes 0 and 8 hold the gate totals.
        v0 += __shfl_xor(v0, 1, 64);  v1 += __shfl_xor(v1, 1, 64);
        v0 += __shfl_xor(v0, 2, 64);  v1 += __shfl_xor(v1, 2, 64);
        v0 += __shfl_xor(v0, 4, 64);  v1 += __shfl_xor(v1, 4, 64);
        v0 += __shfl_xor(v0, 16, 64); v1 += __shfl_xor(v1, 16, 64);
        v0 += __shfl_xor(v0, 32, 64); v1 += __shfl_xor(v1, 32, 64);
        if ((lane & 55) == 0) {                   // lanes 0 and 8
            const int gg = (lane >> 3) & 1;
            qpart[blockIdx.x * 4 + gg]     = v0;  // gates f(0)/i(1)
            qpart[blockIdx.x * 4 + gg + 2] = v1;  // gates g(2)/o(3)
        }
    }
}

// ======= Pass 2: reduce qpart[512][4] + elementwise LSTM update ===========
// cx: NORMAL load (re-read every replay -> keep L3-resident).
// out: NON-TEMPORAL store (write-once stream -> don't evict inputs from L3).
extern "C" __global__ __launch_bounds__(256)
void p3_elementwise(const float* __restrict__ cx, const float* __restrict__ qpart,
                    float* __restrict__ out)
{
    __shared__ float qs[4][4];                  // [wave][gate]
    const int tid  = threadIdx.x;
    const int wave = tid >> 6;
    const int lane = tid & 63;

    // block-local reduce of qpart[512][4]: two f32x4 per thread
    const f32x4* qp4 = (const f32x4*)qpart;
    f32x4 qa = qp4[tid];
    f32x4 qb = qp4[tid + 256];
    f32x4 qp = {qa.x + qb.x, qa.y + qb.y, qa.z + qb.z, qa.w + qb.w};
#pragma unroll
    for (int m = 1; m <= 32; m <<= 1) {
        qp.x += __shfl_xor(qp.x, m, 64);
        qp.y += __shfl_xor(qp.y, m, 64);
        qp.z += __shfl_xor(qp.z, m, 64);
        qp.w += __shfl_xor(qp.w, m, 64);
    }
    if (lane == 0) {
        qs[wave][0] = qp.x; qs[wave][1] = qp.y;
        qs[wave][2] = qp.z; qs[wave][3] = qp.w;
    }
    __syncthreads();
    const float qf = qs[0][0] + qs[1][0] + qs[2][0] + qs[3][0];
    const float qi = qs[0][1] + qs[1][1] + qs[2][1] + qs[3][1];
    const float qg = qs[0][2] + qs[1][2] + qs[2][2] + qs[3][2];
    const float qo = qs[0][3] + qs[1][3] + qs[2][3] + qs[3][3];

    const float f  = 1.f / (1.f + expf(-qf));
    const float ii = 1.f / (1.f + expf(-qi));
    const float g  = tanhf(qg);
    const float o  = 1.f / (1.f + expf(-qo));
    const float ig = ii * g;

    const size_t N  = (size_t)B_ROWS * HIDDEN;
    const size_t N4 = N >> 2;
    const f32x4* cx4 = (const f32x4*)cx;
    f32x4* outh = (f32x4*)out;
    f32x4* outc = (f32x4*)(out + N);

    for (size_t idx = (size_t)blockIdx.x * blockDim.x + tid; idx < N4;
         idx += (size_t)gridDim.x * blockDim.x) {
        f32x4 c = cx4[idx];                       // L3-resident across replays
        f32x4 cn, hn;
        cn.x = fmaf(f, c.x, ig);
        cn.y = fmaf(f, c.y, ig);
        cn.z = fmaf(f, c.z, ig);
        cn.w = fmaf(f, c.w, ig);
        hn.x = o * tanhf(cn.x);
        hn.y = o * tanhf(cn.y);
        hn.z = o * tanhf(cn.z);
        hn.w = o * tanhf(cn.w);
        __builtin_nontemporal_store(cn, outc + idx);
        __builtin_nontemporal_store(hn, outh + idx);
    }
}

// ---------------- launcher: TWO dispatches, no atomics, no memset ---------
extern "C" void kernel_launch(void* const* d_in, const int* in_sizes, int n_in,
                              void* d_out, int out_size, void* d_ws, size_t ws_size,
                              hipStream_t stream)
{
    const float* x  = (const float*)d_in[0];
    const float* hx = (const float*)d_in[1];
    const float* cx = (const float*)d_in[2];
    const float* Wf = (const float*)d_in[3];
    const float* bf = (const float*)d_in[4];
    const float* Wi = (const float*)d_in[5];
    const float* bi = (const float*)d_in[6];
    const float* Wg = (const float*)d_in[7];
    const float* bg = (const float*)d_in[8];
    const float* Wo = (const float*)d_in[9];
    const float* bo = (const float*)d_in[10];
    float* out = (float*)d_out;

    float* qpart = (float*)d_ws;   // [512][4] f32, fully overwritten each call

    p1_full<<<dim3(GRID1), dim3(TPB1), 0, stream>>>(
        x, hx, Wf, Wi, Wg, Wo, bf, bi, bg, bo, qpart);
    p3_elementwise<<<dim3(2048), dim3(256), 0, stream>>>(cx, qpart, out);
}